// Round 6
// baseline (132.058 us; speedup 1.0000x reference)
//
#include <hip/hip_runtime.h>
#include <math.h>

// Problem constants (match reference)
constexpr int B_ = 32;
constexpr int C_ = 32;
constexpr int RES_ = 16;
constexpr int G_ = RES_ * RES_ * RES_;   // 4096
constexpr int N_ = 16384;
constexpr int H_ = 64;
// sqrt(3)/RES
__device__ constexpr float REG_THR = 0.10825317547305483f;

// ---------------------------------------------------------------------------
// Single fused kernel. Block = (batch b, 128-cell tile [c0, c0+128)).
//
// Monotonicity of idx in n means this tile's points are the contiguous range
// [cum[c0-1], cum[c0+127]) -- so the whole pipeline fuses:
//   phase 0: block-local scan of counts[b][0 .. c0+128) -> s_cum (absolute)
//   phase 1: hx tile (128 cells x 64 h) into LDS
//            (2 threads/cell, readfirstlane h-offset -> scalar weight loads;
//             round-4 showed divergent weight addrs cost 43 us)
//   phase 2: per-point: 7-step binary search in s_cum, relu(hx + W1r) dot W2,
//            grid offset computed EXACTLY from idx bits ((2i+1-16)/32 is
//            representable), coalesced out/reg stores.
// No hx HBM round-trip (was 33.5 MB write + read), no grid_o/cum reads,
// no workspace, one launch.
//
// LDS: s_hx 128*68*4 = 34816 B (PAD=68 -> 272 B rows, 16 B aligned for
// float4 ds ops) + s_cum 129*4 + s_part 256*4 ~= 36.2 KB -> 4 blocks/CU.
// ---------------------------------------------------------------------------
constexpr int TC = 128;      // cells per block
constexpr int PADF = 68;     // floats per hx row (16B-aligned stride)

__global__ __launch_bounds__(256) void fused_kernel(
    const float* __restrict__ x, const int* __restrict__ counts,
    const float* __restrict__ b_rnd, const float* __restrict__ W1,
    const float* __restrict__ b1, const float* __restrict__ W2,
    const float* __restrict__ b2, float* __restrict__ out0,
    float* __restrict__ reg_out) {
    const int b = blockIdx.y;
    const int c0 = blockIdx.x * TC;
    const int t = threadIdx.x;

    __shared__ float s_hx[TC * PADF];
    __shared__ int s_cum[TC + 1];   // [0] = cum[c0-1], [1+i] = cum[c0+i]
    __shared__ int s_part[256];

    // ---- phase 0: scan counts[b][0 .. c0+128) ----
    const int limit = c0 + TC;
    const int* cb = counts + b * G_;
    const int base = t * 16;
    int loc[16];
    int s = 0;
#pragma unroll
    for (int i = 0; i < 16; ++i) {
        const int v = (base + i < limit) ? cb[base + i] : 0;
        s += v;
        loc[i] = s;
    }
    s_part[t] = s;
    __syncthreads();
    for (int off = 1; off < 256; off <<= 1) {
        int v = (t >= off) ? s_part[t - off] : 0;
        __syncthreads();
        s_part[t] += v;
        __syncthreads();
    }
    const int prev = (t > 0) ? s_part[t - 1] : 0;
#pragma unroll
    for (int i = 0; i < 16; ++i) {
        const int cell = base + i;
        const int cv = prev + loc[i];
        const int r = cell - c0;
        if (r >= 0 && r < TC) s_cum[1 + r] = cv;
        if (cell == c0 - 1) s_cum[0] = cv;
    }
    if (t == 0 && c0 == 0) s_cum[0] = 0;

    // ---- phase 1: hx tile into LDS ----
    const int cell_l = t & (TC - 1);
    const int hh = __builtin_amdgcn_readfirstlane((t >> 7) * 32);

    const float* xb = x + ((size_t)b * C_) * G_ + c0 + cell_l;
    float xv[C_];
#pragma unroll
    for (int c = 0; c < C_; ++c) xv[c] = xb[(size_t)c * G_];

    float* row = s_hx + cell_l * PADF + hh;
#pragma unroll 2
    for (int q = 0; q < 8; ++q) {   // 8 groups of 4 h -> ds_write_b128
        float a[4];
#pragma unroll
        for (int j = 0; j < 4; ++j) {
            const int h = hh + q * 4 + j;
            float acc = b1[h];
            const float* w = W1 + h * 34;
#pragma unroll
            for (int c = 0; c < C_; ++c) acc = fmaf(w[c], xv[c], acc);
            a[j] = acc;
        }
        *(float4*)(row + q * 4) = make_float4(a[0], a[1], a[2], a[3]);
    }
    __syncthreads();

    // ---- phase 2: this tile's point range ----
    const int p_start = s_cum[0];
    const int p_end = s_cum[TC];

    for (int p = p_start + t; p < p_end; p += 256) {
        // smallest i in [0,128) with s_cum[1+i] > p
        int lo = 0, hi = TC - 1;
#pragma unroll
        for (int it = 0; it < 7; ++it) {
            const int mid = (lo + hi) >> 1;
            if (s_cum[1 + mid] > p) hi = mid; else lo = mid + 1;
        }
        const int ci = lo;            // local cell
        const int idx = c0 + ci;      // global cell

        const float r0 = b_rnd[((size_t)b * 2 + 0) * N_ + p];
        const float r1 = b_rnd[((size_t)b * 2 + 1) * N_ + p];
        const float* hp = s_hx + ci * PADF;

        float o0 = b2[0], o1 = b2[1], o2 = b2[2];
#pragma unroll
        for (int hc = 0; hc < H_ / 4; ++hc) {
            const float4 v = *(const float4*)(hp + hc * 4);
            const float vv[4] = {v.x, v.y, v.z, v.w};
#pragma unroll
            for (int j = 0; j < 4; ++j) {
                const int h = hc * 4 + j;
                float hv = vv[j];
                hv = fmaf(W1[h * 34 + 32], r0, hv);
                hv = fmaf(W1[h * 34 + 33], r1, hv);
                hv = fmaxf(hv, 0.0f);
                o0 = fmaf(W2[0 * H_ + h], hv, o0);
                o1 = fmaf(W2[1 * H_ + h], hv, o1);
                o2 = fmaf(W2[2 * H_ + h], hv, o2);
            }
        }

        const float nrm = sqrtf(o0 * o0 + o1 * o1 + o2 * o2);
        const float reg = fmaxf(nrm - REG_THR, 0.0f);

        // grid_o[k][idx] = (i_k + 0.5)/16 - 0.5, exact in fp32 from idx bits
        o0 += (float)((idx >> 8) & 15) * 0.0625f - 0.46875f;
        o1 += (float)((idx >> 4) & 15) * 0.0625f - 0.46875f;
        o2 += (float)(idx & 15) * 0.0625f - 0.46875f;

        float* op = out0 + ((size_t)b * 3) * N_ + p;
        op[0]              = o0;
        op[N_]             = o1;
        op[2 * (size_t)N_] = o2;
        reg_out[(size_t)b * N_ + p] = reg;
    }
}

// ---------------------------------------------------------------------------
extern "C" void kernel_launch(void* const* d_in, const int* in_sizes, int n_in,
                              void* d_out, int out_size, void* d_ws, size_t ws_size,
                              hipStream_t stream) {
    const float* x      = (const float*)d_in[0];  // (B, C, RES, RES, RES)
    const int*   counts = (const int*)  d_in[1];  // (B, G)
    const float* b_rnd  = (const float*)d_in[2];  // (B, 2, N)
    // d_in[3] = grid_o: unused (recomputed exactly from idx bits)
    const float* W1     = (const float*)d_in[4];  // (H, C+2)
    const float* b1     = (const float*)d_in[5];  // (H,)
    const float* W2     = (const float*)d_in[6];  // (3, H)
    const float* b2     = (const float*)d_in[7];  // (3,)

    float* out  = (float*)d_out;                  // (B, 3, N) then (B, N)
    float* rout = out + (size_t)B_ * 3 * N_;

    dim3 grid(G_ / TC, B_);
    fused_kernel<<<grid, 256, 0, stream>>>(x, counts, b_rnd, W1, b1, W2, b2,
                                           out, rout);
}

// Round 7
// 114.537 us; speedup vs baseline: 1.1530x; 1.1530x over previous
//
#include <hip/hip_runtime.h>
#include <math.h>

// Problem constants (match reference)
constexpr int B_ = 32;
constexpr int C_ = 32;
constexpr int RES_ = 16;
constexpr int G_ = RES_ * RES_ * RES_;   // 4096
constexpr int N_ = 16384;
constexpr int H_ = 64;
// sqrt(3)/RES
__device__ constexpr float REG_THR = 0.10825317547305483f;

// ---------------------------------------------------------------------------
// Kernel 1: per-batch inclusive scan of counts (4096 cells) -> cum[b][G].
// ---------------------------------------------------------------------------
__global__ __launch_bounds__(256) void scan_kernel(const int* __restrict__ counts,
                                                   int* __restrict__ cum) {
    const int b = blockIdx.x;
    const int* cb = counts + b * G_;
    int* ob = cum + b * G_;

    __shared__ int partials[256];
    const int t = threadIdx.x;
    const int base = t * 16;

    int local[16];
    int s = 0;
#pragma unroll
    for (int i = 0; i < 16; ++i) {
        s += cb[base + i];
        local[i] = s;
    }
    partials[t] = s;
    __syncthreads();

    for (int off = 1; off < 256; off <<= 1) {
        int v = (t >= off) ? partials[t - off] : 0;
        __syncthreads();
        partials[t] += v;
        __syncthreads();
    }
    const int prev = (t > 0) ? partials[t - 1] : 0;

#pragma unroll
    for (int i = 0; i < 16; ++i) ob[base + i] = prev + local[i];
}

// ---------------------------------------------------------------------------
// Kernel 2 (Stage A): hx[b, cell, h] = b1[h] + sum_c W1[h,c] * x[b,c,cell]
//
// Cost-model history: R3 = 5.8x write-amp (fixed via LDS copy-out);
// R4 = divergent weight addrs -> per-lane loads (fixed via readfirstlane);
// R5 = still ~30 us: only 4 blocks/CU (33 KB LDS) -> 4 waves/SIMD, with
// correlated s_load-wait + x-load-wait stalls. This round: 64 cells/block,
// 4 h-groups of 16 (hh = waveid*16, exactly wave-uniform), LDS 16.6 KB ->
// 8 blocks/CU = 8 waves/SIMD, halved per-wave weight stream. PAD=65 keeps
// all LDS b32 phases conflict-free.
// ---------------------------------------------------------------------------
constexpr int TCELL = 64;    // cells per block
constexpr int PAD = H_ + 1;  // 65

__global__ __launch_bounds__(256) void hx_kernel(const float* __restrict__ x,
                                                 const float* __restrict__ W1,
                                                 const float* __restrict__ b1,
                                                 float* __restrict__ hx) {
    const int b = blockIdx.y;
    const int tile = blockIdx.x * TCELL;
    const int t = threadIdx.x;
    const int cell_l = t & 63;                 // lane = cell
    // wave id (t>>6) is exactly per-wave uniform; 16 h per wave.
    const int hh = __builtin_amdgcn_readfirstlane((t >> 6) * 16);

    __shared__ float s_hx[TCELL * PAD];        // 16640 B

    // Coalesced x loads: 64 lanes -> 64 consecutive cells (each wave loads
    // the same tile; redundant copies hit L1).
    const float* xb = x + ((size_t)b * C_) * G_ + tile + cell_l;
    float xv[C_];
#pragma unroll
    for (int c = 0; c < C_; ++c) xv[c] = xb[(size_t)c * G_];

    // 16 h-values per thread; weights at wave-uniform addresses (s_load).
    float* row = s_hx + cell_l * PAD + hh;
#pragma unroll 4
    for (int j = 0; j < 16; ++j) {
        const int h = hh + j;
        float acc = b1[h];
        const float* w = W1 + h * 34;
#pragma unroll
        for (int c = 0; c < C_; ++c) acc = fmaf(w[c], xv[c], acc);
        row[j] = acc;   // bank = (65*cell + h)%32 = (cell+h)%32: conflict-free
    }
    __syncthreads();

    // Linear coalesced copy-out: 64*64 = 4096 floats = 1024 float4.
    float* ob = hx + ((size_t)b * G_ + tile) * H_;
#pragma unroll
    for (int k = 0; k < 4; ++k) {
        const int L = (t + k * 256) * 4;       // linear float index
        const int cell = L >> 6;               // L / 64
        const int h = L & 63;
        const float* s = s_hx + cell * PAD + h;
        *(float4*)(ob + L) = make_float4(s[0], s[1], s[2], s[3]);
    }
}

// ---------------------------------------------------------------------------
// Kernel 3 (Stage B): one thread per (b, n) point.
//   idx = searchsorted(cum[b], n, 'right')  (binary search, LDS copy)
//   h   = relu(hx[b, idx, :] + W1[:,32]*r0 + W1[:,33]*r1)
//   out = W2 @ h + b2;  out += grid offset (exact from idx bits);
//   reg = clip(||out|| - sqrt(3)/RES, 0)
// ---------------------------------------------------------------------------
__global__ __launch_bounds__(256) void point_kernel(
    const float* __restrict__ hx, const float* __restrict__ b_rnd,
    const float* __restrict__ W1, const float* __restrict__ W2,
    const float* __restrict__ b2, const int* __restrict__ cum,
    float* __restrict__ out0, float* __restrict__ reg_out) {
    const int b = blockIdx.y;
    const int n = blockIdx.x * 256 + threadIdx.x;
    const int t = threadIdx.x;

    __shared__ int s_cum[G_];
    const int* cb = cum + b * G_;
#pragma unroll
    for (int i = 0; i < G_ / 256; ++i) s_cum[t + i * 256] = cb[t + i * 256];
    __syncthreads();

    int lo = 0, hi = G_ - 1;
#pragma unroll
    for (int it = 0; it < 12; ++it) {
        const int mid = (lo + hi) >> 1;
        if (s_cum[mid] > n) hi = mid; else lo = mid + 1;
        if (lo >= hi) hi = lo;
    }
    const int idx = lo;

    const float r0 = b_rnd[((size_t)b * 2 + 0) * N_ + n];
    const float r1 = b_rnd[((size_t)b * 2 + 1) * N_ + n];
    const float* hp = hx + ((size_t)b * G_ + idx) * H_;

    float o0 = b2[0], o1 = b2[1], o2 = b2[2];
#pragma unroll 4
    for (int hc = 0; hc < H_ / 4; ++hc) {
        const float4 v = *(const float4*)(hp + hc * 4);
        const float vv[4] = {v.x, v.y, v.z, v.w};
#pragma unroll
        for (int j = 0; j < 4; ++j) {
            const int h = hc * 4 + j;
            float hv = vv[j];
            hv = fmaf(W1[h * 34 + 32], r0, hv);
            hv = fmaf(W1[h * 34 + 33], r1, hv);
            hv = fmaxf(hv, 0.0f);
            o0 = fmaf(W2[0 * H_ + h], hv, o0);
            o1 = fmaf(W2[1 * H_ + h], hv, o1);
            o2 = fmaf(W2[2 * H_ + h], hv, o2);
        }
    }

    const float nrm = sqrtf(o0 * o0 + o1 * o1 + o2 * o2);
    const float reg = fmaxf(nrm - REG_THR, 0.0f);

    // grid_o[k][idx] = (i_k + 0.5)/16 - 0.5, exact in fp32 from idx bits
    // (verified bit-exact vs reference in round 6: absmax unchanged).
    o0 += (float)((idx >> 8) & 15) * 0.0625f - 0.46875f;
    o1 += (float)((idx >> 4) & 15) * 0.0625f - 0.46875f;
    o2 += (float)(idx & 15) * 0.0625f - 0.46875f;

    float* p = out0 + ((size_t)b * 3) * N_ + n;
    p[0]              = o0;
    p[N_]             = o1;
    p[2 * (size_t)N_] = o2;
    reg_out[(size_t)b * N_ + n] = reg;
}

// ---------------------------------------------------------------------------
extern "C" void kernel_launch(void* const* d_in, const int* in_sizes, int n_in,
                              void* d_out, int out_size, void* d_ws, size_t ws_size,
                              hipStream_t stream) {
    const float* x      = (const float*)d_in[0];  // (B, C, RES, RES, RES)
    const int*   counts = (const int*)  d_in[1];  // (B, G)
    const float* b_rnd  = (const float*)d_in[2];  // (B, 2, N)
    // d_in[3] = grid_o: unused (recomputed exactly from idx bits)
    const float* W1     = (const float*)d_in[4];  // (H, C+2)
    const float* b1     = (const float*)d_in[5];  // (H,)
    const float* W2     = (const float*)d_in[6];  // (3, H)
    const float* b2     = (const float*)d_in[7];  // (3,)

    float* out  = (float*)d_out;                      // (B, 3, N) then (B, N)
    float* rout = out + (size_t)B_ * 3 * N_;

    int*   cum = (int*)d_ws;                          // B*G ints   = 512 KB
    float* hx  = (float*)((char*)d_ws + (size_t)B_ * G_ * sizeof(int));
                                                      // B*G*H fp32 = 33.5 MB

    scan_kernel<<<B_, 256, 0, stream>>>(counts, cum);

    dim3 gridA(G_ / TCELL, B_);
    hx_kernel<<<gridA, 256, 0, stream>>>(x, W1, b1, hx);

    dim3 gridB(N_ / 256, B_);
    point_kernel<<<gridB, 256, 0, stream>>>(hx, b_rnd, W1, W2, b2,
                                            cum, out, rout);
}

// Round 8
// 110.106 us; speedup vs baseline: 1.1994x; 1.0402x over previous
//
#include <hip/hip_runtime.h>
#include <math.h>

// Problem constants (match reference)
constexpr int B_ = 32;
constexpr int C_ = 32;
constexpr int RES_ = 16;
constexpr int G_ = RES_ * RES_ * RES_;   // 4096
constexpr int N_ = 16384;
constexpr int H_ = 64;
// sqrt(3)/RES
__device__ constexpr float REG_THR = 0.10825317547305483f;

// float -> bf16 bits, round-to-nearest-even (values are finite here).
__device__ __forceinline__ unsigned short f2bf(float f) {
    union { float f; unsigned int u; } v; v.f = f;
    const unsigned int r = v.u + 0x7FFFu + ((v.u >> 16) & 1u);
    return (unsigned short)(r >> 16);
}

// ---------------------------------------------------------------------------
// Kernel 1: per-batch inclusive scan of counts (4096 cells) -> cum[b][G].
// ---------------------------------------------------------------------------
__global__ __launch_bounds__(256) void scan_kernel(const int* __restrict__ counts,
                                                   int* __restrict__ cum) {
    const int b = blockIdx.x;
    const int* cb = counts + b * G_;
    int* ob = cum + b * G_;

    __shared__ int partials[256];
    const int t = threadIdx.x;
    const int base = t * 16;

    int local[16];
    int s = 0;
#pragma unroll
    for (int i = 0; i < 16; ++i) {
        s += cb[base + i];
        local[i] = s;
    }
    partials[t] = s;
    __syncthreads();

    for (int off = 1; off < 256; off <<= 1) {
        int v = (t >= off) ? partials[t - off] : 0;
        __syncthreads();
        partials[t] += v;
        __syncthreads();
    }
    const int prev = (t > 0) ? partials[t - 1] : 0;

#pragma unroll
    for (int i = 0; i < 16; ++i) ob[base + i] = prev + local[i];
}

// ---------------------------------------------------------------------------
// Kernel 2 (Stage A): hx_bf[b, cell, h] = bf16( b1[h] + sum_c W1[h,c]*x[..] )
//
// Stall history: R3 write-amp (fixed: LDS copy-out); R4 divergent weight
// addrs (fixed: readfirstlane); R5/R7 still ~25 us at VALUBusy 21% with 4
// AND 8 waves/SIMD -> not a wave-depth problem. Surviving theory: the
// s_load weight stream (544 floats/wave, ~40 free SGPRs -> ~2 chunks in
// flight) serializes every wave identically on lgkmcnt. Fix: W1 staged in
// LDS once per block; per-h rows read wave-uniform (HW broadcast,
// conflict-free, no SGPR budget). Output stored as bf16 (RNE) -> halves
// the hx round-trip; error ~2e-4 << 1.5e-2 threshold.
//
// LDS: s_w1 64 rows x 36 floats (144 B, 16B-aligned; [34]=b1) = 9.2 KB
//    + s_hx 64 x 65 fp32 = 16.6 KB  -> 25.9 KB -> 6 blocks/CU.
// ---------------------------------------------------------------------------
constexpr int TCELL = 64;     // cells per block
constexpr int PAD = H_ + 1;   // 65: b32 LDS phases conflict-free
constexpr int WROW = 36;      // W1 LDS row stride (floats)

__global__ __launch_bounds__(256) void hx_kernel(const float* __restrict__ x,
                                                 const float* __restrict__ W1,
                                                 const float* __restrict__ b1,
                                                 unsigned short* __restrict__ hxb) {
    const int b = blockIdx.y;
    const int tile = blockIdx.x * TCELL;
    const int t = threadIdx.x;
    const int cell_l = t & 63;                 // lane = cell
    const int hh = __builtin_amdgcn_readfirstlane((t >> 6) * 16);

    __shared__ float __align__(16) s_w1[H_ * WROW];
    __shared__ float s_hx[TCELL * PAD];

    // Cooperative W1 fill (2176 floats) + b1 into the row pad.
    for (int i = t; i < H_ * 34; i += 256) {
        const int r = i / 34;
        const int c = i - r * 34;
        s_w1[r * WROW + c] = W1[i];
    }
    if (t < H_) s_w1[t * WROW + 34] = b1[t];

    // Coalesced x loads (issue before the barrier to overlap HBM latency).
    const float* xb = x + ((size_t)b * C_) * G_ + tile + cell_l;
    float xv[C_];
#pragma unroll
    for (int c = 0; c < C_; ++c) xv[c] = xb[(size_t)c * G_];
    __syncthreads();

    // 16 h per thread; weight rows from LDS at wave-uniform addresses
    // (broadcast reads, vectorizable to ds_read_b128: rows 16B-aligned).
    float* row = s_hx + cell_l * PAD + hh;
#pragma unroll 4
    for (int j = 0; j < 16; ++j) {
        const float* w = s_w1 + (hh + j) * WROW;
        float acc = w[34];                     // b1[h]
#pragma unroll
        for (int c = 0; c < C_; ++c) acc = fmaf(w[c], xv[c], acc);
        row[j] = acc;   // bank = (cell + h)%32 across lanes: conflict-free
    }
    __syncthreads();

    // Copy-out: convert to bf16, pack, linear coalesced uint4 stores.
    // LDS reads: 8 consecutive b32/thread -> <=2-way bank aliasing (free).
    unsigned short* ob = hxb + ((size_t)b * G_ + tile) * H_;
#pragma unroll
    for (int k = 0; k < 2; ++k) {
        const int L = (t + k * 256) * 8;       // linear element index
        const int cell = L >> 6;
        const int h = L & 63;
        const float* s = s_hx + cell * PAD + h;
        unsigned int us[4];
#pragma unroll
        for (int q = 0; q < 4; ++q) {
            const unsigned int lo = f2bf(s[2 * q]);
            const unsigned int hi = f2bf(s[2 * q + 1]);
            us[q] = lo | (hi << 16);
        }
        *(uint4*)(ob + L) = make_uint4(us[0], us[1], us[2], us[3]);
    }
}

// ---------------------------------------------------------------------------
// Kernel 3 (Stage B): one thread per (b, n) point.
//   idx = searchsorted(cum[b], n, 'right')  (binary search, LDS copy)
//   h   = relu(bf16->f32(hx[b,idx,:]) + W1[:,32]*r0 + W1[:,33]*r1)
//   out = W2 @ h + b2;  out += exact grid offset;  reg = clip(|out|-thr, 0)
// hx row = 128 B contiguous -> 8 uint4 loads; ~4 points/cell -> L1 reuse.
// ---------------------------------------------------------------------------
__global__ __launch_bounds__(256) void point_kernel(
    const unsigned short* __restrict__ hxb, const float* __restrict__ b_rnd,
    const float* __restrict__ W1, const float* __restrict__ W2,
    const float* __restrict__ b2, const int* __restrict__ cum,
    float* __restrict__ out0, float* __restrict__ reg_out) {
    const int b = blockIdx.y;
    const int n = blockIdx.x * 256 + threadIdx.x;
    const int t = threadIdx.x;

    __shared__ int s_cum[G_];
    const int* cb = cum + b * G_;
#pragma unroll
    for (int i = 0; i < G_ / 256; ++i) s_cum[t + i * 256] = cb[t + i * 256];
    __syncthreads();

    int lo = 0, hi = G_ - 1;
#pragma unroll
    for (int it = 0; it < 12; ++it) {
        const int mid = (lo + hi) >> 1;
        if (s_cum[mid] > n) hi = mid; else lo = mid + 1;
        if (lo >= hi) hi = lo;
    }
    const int idx = lo;

    const float r0 = b_rnd[((size_t)b * 2 + 0) * N_ + n];
    const float r1 = b_rnd[((size_t)b * 2 + 1) * N_ + n];
    const unsigned short* hp = hxb + ((size_t)b * G_ + idx) * H_;

    float o0 = b2[0], o1 = b2[1], o2 = b2[2];
#pragma unroll
    for (int g = 0; g < 8; ++g) {              // 8 h per group, one uint4
        const uint4 u = *(const uint4*)(hp + g * 8);
        const unsigned int uw[4] = {u.x, u.y, u.z, u.w};
        float hvv[8];
#pragma unroll
        for (int q = 0; q < 4; ++q) {
            union { unsigned int u; float f; } a, bwd;
            a.u = uw[q] << 16;                 // even h
            bwd.u = uw[q] & 0xFFFF0000u;       // odd h
            hvv[2 * q] = a.f;
            hvv[2 * q + 1] = bwd.f;
        }
#pragma unroll
        for (int j = 0; j < 8; ++j) {
            const int h = g * 8 + j;
            float hv = hvv[j];
            hv = fmaf(W1[h * 34 + 32], r0, hv);
            hv = fmaf(W1[h * 34 + 33], r1, hv);
            hv = fmaxf(hv, 0.0f);
            o0 = fmaf(W2[0 * H_ + h], hv, o0);
            o1 = fmaf(W2[1 * H_ + h], hv, o1);
            o2 = fmaf(W2[2 * H_ + h], hv, o2);
        }
    }

    const float nrm = sqrtf(o0 * o0 + o1 * o1 + o2 * o2);
    const float reg = fmaxf(nrm - REG_THR, 0.0f);

    // grid_o[k][idx] = (i_k + 0.5)/16 - 0.5, exact in fp32 from idx bits.
    o0 += (float)((idx >> 8) & 15) * 0.0625f - 0.46875f;
    o1 += (float)((idx >> 4) & 15) * 0.0625f - 0.46875f;
    o2 += (float)(idx & 15) * 0.0625f - 0.46875f;

    float* p = out0 + ((size_t)b * 3) * N_ + n;
    p[0]              = o0;
    p[N_]             = o1;
    p[2 * (size_t)N_] = o2;
    reg_out[(size_t)b * N_ + n] = reg;
}

// ---------------------------------------------------------------------------
extern "C" void kernel_launch(void* const* d_in, const int* in_sizes, int n_in,
                              void* d_out, int out_size, void* d_ws, size_t ws_size,
                              hipStream_t stream) {
    const float* x      = (const float*)d_in[0];  // (B, C, RES, RES, RES)
    const int*   counts = (const int*)  d_in[1];  // (B, G)
    const float* b_rnd  = (const float*)d_in[2];  // (B, 2, N)
    // d_in[3] = grid_o: unused (recomputed exactly from idx bits)
    const float* W1     = (const float*)d_in[4];  // (H, C+2)
    const float* b1     = (const float*)d_in[5];  // (H,)
    const float* W2     = (const float*)d_in[6];  // (3, H)
    const float* b2     = (const float*)d_in[7];  // (3,)

    float* out  = (float*)d_out;                  // (B, 3, N) then (B, N)
    float* rout = out + (size_t)B_ * 3 * N_;

    int* cum = (int*)d_ws;                        // B*G ints = 512 KB
    unsigned short* hxb =
        (unsigned short*)((char*)d_ws + (size_t)B_ * G_ * sizeof(int));
                                                  // B*G*H bf16 = 16.8 MB

    scan_kernel<<<B_, 256, 0, stream>>>(counts, cum);

    dim3 gridA(G_ / TCELL, B_);
    hx_kernel<<<gridA, 256, 0, stream>>>(x, W1, b1, hxb);

    dim3 gridB(N_ / 256, B_);
    point_kernel<<<gridB, 256, 0, stream>>>(hxb, b_rnd, W1, W2, b2,
                                            cum, out, rout);
}